// Round 2
// baseline (836.037 us; speedup 1.0000x reference)
//
#include <hip/hip_runtime.h>
#include <hip/hip_bf16.h>
#include <hip/hip_fp16.h>

typedef float f32x4 __attribute__((ext_vector_type(4)));
typedef short short8 __attribute__((ext_vector_type(8)));
typedef _Float16 h4 __attribute__((ext_vector_type(4)));
typedef unsigned short u16;
typedef unsigned int u32;

#define LDK 40  // padded LDS k-stride (bf16 elems): 80B rows -> 2-way bank aliasing (free)

__device__ __forceinline__ u16 bf16_rne(float x) {
  u32 u = __float_as_uint(x);
  u += 0x7FFFu + ((u >> 16) & 1u);
  return (u16)(u >> 16);
}

// split fp32 -> hi (truncated bf16) + lo (bf16 of remainder); hi+lo ~ 2^-17 rel accurate
__device__ __forceinline__ void split_store4(u16* hi, u16* lo, float4 v) {
  u32 u0 = __float_as_uint(v.x), u1 = __float_as_uint(v.y);
  u32 u2 = __float_as_uint(v.z), u3 = __float_as_uint(v.w);
  float r0 = v.x - __uint_as_float(u0 & 0xFFFF0000u);
  float r1 = v.y - __uint_as_float(u1 & 0xFFFF0000u);
  float r2 = v.z - __uint_as_float(u2 & 0xFFFF0000u);
  float r3 = v.w - __uint_as_float(u3 & 0xFFFF0000u);
  uint2 hp, lp;
  hp.x = (u0 >> 16) | (u1 & 0xFFFF0000u);
  hp.y = (u2 >> 16) | (u3 & 0xFFFF0000u);
  lp.x = (__float_as_uint(r0) >> 16) | (__float_as_uint(r1) & 0xFFFF0000u);
  lp.y = (__float_as_uint(r2) >> 16) | (__float_as_uint(r3) & 0xFFFF0000u);
  *(uint2*)hi = hp;
  *(uint2*)lo = lp;
}

// round 4 fp32 -> 4 bf16 (RNE), packed store
__device__ __forceinline__ void rne_store4(u16* dst, float4 v) {
  uint2 p;
  p.x = (u32)bf16_rne(v.x) | ((u32)bf16_rne(v.y) << 16);
  p.y = (u32)bf16_rne(v.z) | ((u32)bf16_rne(v.w) << 16);
  *(uint2*)dst = p;
}

// ---------------------------------------------------------------------------
// Projection: Y = X @ W^T + b.  X:[M,1024] fp32 (split hi/lo in LDS),
// W:[1024,1024] fp32 (rounded bf16 in LDS).  2 MFMA per pair: (Xh+Xl)*Wbf16.
// mode 0: write Yhi/Ylo split bf16 [M,1024]   (q)
// mode 2: write Yhi plain bf16 RNE [M,1024]   (k)
// mode 1: write Yt plain bf16 transposed [b][1024][2048]  (v)
// ---------------------------------------------------------------------------
__global__ __launch_bounds__(256)
void proj_kernel(const float* __restrict__ X, const float* __restrict__ W,
                 const float* __restrict__ bias,
                 u16* __restrict__ Yhi, u16* __restrict__ Ylo,
                 u16* __restrict__ Yt, int mode)
{
  __shared__ __align__(16) u16 Ah[128 * LDK];
  __shared__ __align__(16) u16 Al[128 * LDK];
  __shared__ __align__(16) u16 Bh[128 * LDK];

  const int tid = threadIdx.x;
  const int m0 = blockIdx.y * 128, n0 = blockIdx.x * 128;
  const int w = tid >> 6, lane = tid & 63;
  const int wm = (w >> 1) * 64, wn = (w & 1) * 64;
  const int lrow = lane & 15, quad = lane >> 4;

  f32x4 acc[4][4];
#pragma unroll
  for (int i = 0; i < 4; ++i)
#pragma unroll
    for (int j = 0; j < 4; ++j) {
      f32x4 z = {0.f, 0.f, 0.f, 0.f};
      acc[i][j] = z;
    }

  const int sr = tid >> 3;  // 0..31 (base row), rows sr+32*i
  const int sc = tid & 7;   // float4 column within 32-wide K tile

  for (int kt = 0; kt < 1024; kt += 32) {
    __syncthreads();
#pragma unroll
    for (int i = 0; i < 4; ++i) {
      int r = sr + 32 * i;
      float4 av = *(const float4*)(X + (size_t)(m0 + r) * 1024 + kt + sc * 4);
      float4 bv = *(const float4*)(W + (size_t)(n0 + r) * 1024 + kt + sc * 4);
      split_store4(&Ah[r * LDK + sc * 4], &Al[r * LDK + sc * 4], av);
      rne_store4(&Bh[r * LDK + sc * 4], bv);
    }
    __syncthreads();

    short8 a_h[4], a_l[4], b_h[4];
#pragma unroll
    for (int i = 0; i < 4; ++i) {
      int ar = (wm + i * 16 + lrow) * LDK + quad * 8;
      int br = (wn + i * 16 + lrow) * LDK + quad * 8;
      a_h[i] = *(const short8*)&Ah[ar];
      a_l[i] = *(const short8*)&Al[ar];
      b_h[i] = *(const short8*)&Bh[br];
    }
#pragma unroll
    for (int i = 0; i < 4; ++i)
#pragma unroll
      for (int j = 0; j < 4; ++j) {
        acc[i][j] = __builtin_amdgcn_mfma_f32_16x16x32_bf16(a_l[i], b_h[j], acc[i][j], 0, 0, 0);
        acc[i][j] = __builtin_amdgcn_mfma_f32_16x16x32_bf16(a_h[i], b_h[j], acc[i][j], 0, 0, 0);
      }
  }

  // epilogue: C layout col=lane&15, row=quad*4+reg  [m89/m91 verified]
#pragma unroll
  for (int j = 0; j < 4; ++j) {
    int gn = n0 + wn + j * 16 + lrow;
    float bj = bias[gn];
#pragma unroll
    for (int i = 0; i < 4; ++i) {
      int gm_base = m0 + wm + i * 16 + quad * 4;
#pragma unroll
      for (int r = 0; r < 4; ++r) {
        float v = acc[i][j][r] + bj;
        int gm = gm_base + r;
        if (mode == 0) {
          u32 u = __float_as_uint(v);
          Yhi[(size_t)gm * 1024 + gn] = (u16)(u >> 16);
          float rem = v - __uint_as_float(u & 0xFFFF0000u);
          Ylo[(size_t)gm * 1024 + gn] = (u16)(__float_as_uint(rem) >> 16);
        } else if (mode == 2) {
          Yhi[(size_t)gm * 1024 + gn] = bf16_rne(v);
        } else {
          int bb = gm >> 11, t = gm & 2047;
          Yt[((size_t)bb * 1024 + gn) * 2048 + t] = bf16_rne(v);
        }
      }
    }
  }
}

// ---------------------------------------------------------------------------
// Scores: S[b,s,t] = scale * q_s . k_t.  q split (hi/lo), k plain bf16.
// 2 MFMA per pair.  Output fp16.
// ---------------------------------------------------------------------------
__global__ __launch_bounds__(256)
void score_kernel(const u16* __restrict__ qh, const u16* __restrict__ ql,
                  const u16* __restrict__ kh, _Float16* __restrict__ S)
{
  __shared__ __align__(16) u16 Ah[128 * LDK];
  __shared__ __align__(16) u16 Al[128 * LDK];
  __shared__ __align__(16) u16 Bh[128 * LDK];

  const int tid = threadIdx.x;
  const int b = blockIdx.z;
  const int m0 = blockIdx.y * 128, n0 = blockIdx.x * 128;
  const u16* qh_b = qh + ((size_t)b * 2048 + m0) * 1024;
  const u16* ql_b = ql + ((size_t)b * 2048 + m0) * 1024;
  const u16* kh_b = kh + ((size_t)b * 2048 + n0) * 1024;

  const int w = tid >> 6, lane = tid & 63;
  const int wm = (w >> 1) * 64, wn = (w & 1) * 64;
  const int lrow = lane & 15, quad = lane >> 4;

  f32x4 acc[4][4];
#pragma unroll
  for (int i = 0; i < 4; ++i)
#pragma unroll
    for (int j = 0; j < 4; ++j) {
      f32x4 z = {0.f, 0.f, 0.f, 0.f};
      acc[i][j] = z;
    }

  const int r1 = tid >> 2, seg = tid & 3;  // 16B chunks: 4 per 32-elem row
  const int r2 = r1 + 64;

  for (int kt = 0; kt < 1024; kt += 32) {
    __syncthreads();
    size_t g1 = (size_t)r1 * 1024 + kt + seg * 8;
    size_t g2 = (size_t)r2 * 1024 + kt + seg * 8;
    int l1 = r1 * LDK + seg * 8, l2 = r2 * LDK + seg * 8;
    *(uint4*)&Ah[l1] = *(const uint4*)(qh_b + g1);
    *(uint4*)&Ah[l2] = *(const uint4*)(qh_b + g2);
    *(uint4*)&Al[l1] = *(const uint4*)(ql_b + g1);
    *(uint4*)&Al[l2] = *(const uint4*)(ql_b + g2);
    *(uint4*)&Bh[l1] = *(const uint4*)(kh_b + g1);
    *(uint4*)&Bh[l2] = *(const uint4*)(kh_b + g2);
    __syncthreads();

    short8 a_h[4], a_l[4], b_h[4];
#pragma unroll
    for (int i = 0; i < 4; ++i) {
      int ar = (wm + i * 16 + lrow) * LDK + quad * 8;
      int br = (wn + i * 16 + lrow) * LDK + quad * 8;
      a_h[i] = *(const short8*)&Ah[ar];
      a_l[i] = *(const short8*)&Al[ar];
      b_h[i] = *(const short8*)&Bh[br];
    }
#pragma unroll
    for (int i = 0; i < 4; ++i)
#pragma unroll
      for (int j = 0; j < 4; ++j) {
        acc[i][j] = __builtin_amdgcn_mfma_f32_16x16x32_bf16(a_l[i], b_h[j], acc[i][j], 0, 0, 0);
        acc[i][j] = __builtin_amdgcn_mfma_f32_16x16x32_bf16(a_h[i], b_h[j], acc[i][j], 0, 0, 0);
      }
  }

  const float scale = 0.03125f;  // 1/sqrt(1024)
#pragma unroll
  for (int j = 0; j < 4; ++j) {
    int gn = n0 + wn + j * 16 + lrow;
#pragma unroll
    for (int i = 0; i < 4; ++i) {
      int gm_base = m0 + wm + i * 16 + quad * 4;
#pragma unroll
      for (int r = 0; r < 4; ++r) {
        int gm = gm_base + r;
        S[((size_t)b * 2048 + gm) * 2048 + gn] = (_Float16)(acc[i][j][r] * scale);
      }
    }
  }
}

// ---------------------------------------------------------------------------
// Row softmax over S[row][0..2047] fp16; writes P bf16 IN PLACE over the row
// (fp16 row and bf16 row are both 4096 B; full row is in registers before any
// write, and each block owns exactly one row).
// ---------------------------------------------------------------------------
__global__ __launch_bounds__(256)
void softmax_kernel(_Float16* __restrict__ S)
{
  const int row = blockIdx.x;
  const int tid = threadIdx.x;
  _Float16* Sr = S + (size_t)row * 2048;
  h4 ah = *(const h4*)(Sr + tid * 4);
  h4 bh = *(const h4*)(Sr + 1024 + tid * 4);
  float a0 = (float)ah.x, a1 = (float)ah.y, a2 = (float)ah.z, a3 = (float)ah.w;
  float b0 = (float)bh.x, b1 = (float)bh.y, b2 = (float)bh.z, b3 = (float)bh.w;

  float m = fmaxf(fmaxf(fmaxf(a0, a1), fmaxf(a2, a3)),
                  fmaxf(fmaxf(b0, b1), fmaxf(b2, b3)));
#pragma unroll
  for (int off = 32; off > 0; off >>= 1) m = fmaxf(m, __shfl_xor(m, off));

  __shared__ float red[4];
  const int wid = tid >> 6, lane = tid & 63;
  if (lane == 0) red[wid] = m;
  __syncthreads();
  m = fmaxf(fmaxf(red[0], red[1]), fmaxf(red[2], red[3]));

  float e0 = __expf(a0 - m), e1 = __expf(a1 - m), e2 = __expf(a2 - m), e3 = __expf(a3 - m);
  float e4 = __expf(b0 - m), e5 = __expf(b1 - m), e6 = __expf(b2 - m), e7 = __expf(b3 - m);
  float s = ((e0 + e1) + (e2 + e3)) + ((e4 + e5) + (e6 + e7));
#pragma unroll
  for (int off = 32; off > 0; off >>= 1) s += __shfl_xor(s, off);
  __syncthreads();
  if (lane == 0) red[wid] = s;
  __syncthreads();
  s = red[0] + red[1] + red[2] + red[3];
  float inv = 1.0f / s;

  u16* P = (u16*)S;
  size_t pb = (size_t)row * 2048;
  uint2 w0, w1;
  w0.x = (u32)bf16_rne(e0 * inv) | ((u32)bf16_rne(e1 * inv) << 16);
  w0.y = (u32)bf16_rne(e2 * inv) | ((u32)bf16_rne(e3 * inv) << 16);
  w1.x = (u32)bf16_rne(e4 * inv) | ((u32)bf16_rne(e5 * inv) << 16);
  w1.y = (u32)bf16_rne(e6 * inv) | ((u32)bf16_rne(e7 * inv) << 16);
  *(uint2*)&P[pb + tid * 4] = w0;
  *(uint2*)&P[pb + 1024 + tid * 4] = w1;
}

// ---------------------------------------------------------------------------
// O[b,s,e] = sum_t P[b,s,t] * V[b,t,e].  P bf16 (row stride 2048), Vt bf16
// transposed [b][e][t] so both operands are K-contiguous. Plain bf16, 1 MFMA.
// ---------------------------------------------------------------------------
__global__ __launch_bounds__(256)
void pv_kernel(const u16* __restrict__ P, const u16* __restrict__ Vt,
               float* __restrict__ O)
{
  __shared__ __align__(16) u16 Ah[128 * LDK];
  __shared__ __align__(16) u16 Bh[128 * LDK];

  const int tid = threadIdx.x;
  const int b = blockIdx.z;
  const int m0 = blockIdx.y * 128, n0 = blockIdx.x * 128;
  const u16* A_b = P + ((size_t)b * 2048 + m0) * 2048;   // row stride 2048 u16
  const u16* B_b = Vt + ((size_t)b * 1024 + n0) * 2048;  // row stride 2048 u16

  const int w = tid >> 6, lane = tid & 63;
  const int wm = (w >> 1) * 64, wn = (w & 1) * 64;
  const int lrow = lane & 15, quad = lane >> 4;

  f32x4 acc[4][4];
#pragma unroll
  for (int i = 0; i < 4; ++i)
#pragma unroll
    for (int j = 0; j < 4; ++j) {
      f32x4 z = {0.f, 0.f, 0.f, 0.f};
      acc[i][j] = z;
    }

  const int r1 = tid >> 2, seg = tid & 3;
  const int r2 = r1 + 64;

  for (int kt = 0; kt < 2048; kt += 32) {
    __syncthreads();
    int l1 = r1 * LDK + seg * 8, l2 = r2 * LDK + seg * 8;
    *(uint4*)&Ah[l1] = *(const uint4*)(A_b + (size_t)r1 * 2048 + kt + seg * 8);
    *(uint4*)&Ah[l2] = *(const uint4*)(A_b + (size_t)r2 * 2048 + kt + seg * 8);
    *(uint4*)&Bh[l1] = *(const uint4*)(B_b + (size_t)r1 * 2048 + kt + seg * 8);
    *(uint4*)&Bh[l2] = *(const uint4*)(B_b + (size_t)r2 * 2048 + kt + seg * 8);
    __syncthreads();

    short8 a_f[4], b_f[4];
#pragma unroll
    for (int i = 0; i < 4; ++i) {
      a_f[i] = *(const short8*)&Ah[(wm + i * 16 + lrow) * LDK + quad * 8];
      b_f[i] = *(const short8*)&Bh[(wn + i * 16 + lrow) * LDK + quad * 8];
    }
#pragma unroll
    for (int i = 0; i < 4; ++i)
#pragma unroll
      for (int j = 0; j < 4; ++j)
        acc[i][j] = __builtin_amdgcn_mfma_f32_16x16x32_bf16(a_f[i], b_f[j], acc[i][j], 0, 0, 0);
  }

#pragma unroll
  for (int j = 0; j < 4; ++j) {
    int gn = n0 + wn + j * 16 + lrow;
#pragma unroll
    for (int i = 0; i < 4; ++i) {
      int gm_base = m0 + wm + i * 16 + quad * 4;
#pragma unroll
      for (int r = 0; r < 4; ++r) {
        int gm = gm_base + r;
        O[((size_t)b * 2048 + gm) * 1024 + gn] = acc[i][j][r];
      }
    }
  }
}

// ---------------------------------------------------------------------------
extern "C" void kernel_launch(void* const* d_in, const int* in_sizes, int n_in,
                              void* d_out, int out_size, void* d_ws, size_t ws_size,
                              hipStream_t stream) {
  const float* x   = (const float*)d_in[0];
  const float* ctx = (const float*)d_in[1];
  const float* Wq  = (const float*)d_in[2];
  const float* bq  = (const float*)d_in[3];
  const float* Wk  = (const float*)d_in[4];
  const float* bk  = (const float*)d_in[5];
  const float* Wv  = (const float*)d_in[6];
  const float* bv  = (const float*)d_in[7];
  float* out = (float*)d_out;

  // workspace layout: qh, ql, kh, vt (4 x 32 MiB bf16) + S (64 MiB fp16) = 192 MiB
  const size_t NQ = (size_t)16384 * 1024;
  const size_t needed = 4 * NQ * sizeof(u16) + (size_t)16384 * 2048 * sizeof(_Float16);
  if (ws_size < needed) return;  // diagnostic: clean absmax failure instead of GPU fault

  u16* qh = (u16*)d_ws;
  u16* ql = qh + NQ;
  u16* kh = ql + NQ;
  u16* vt = kh + NQ;
  _Float16* S = (_Float16*)(vt + NQ);  // 8*2048*2048 fp16; P (bf16) aliases rows

  dim3 blk(256, 1, 1);
  hipLaunchKernelGGL(proj_kernel, dim3(8, 128, 1), blk, 0, stream, x,   Wq, bq, qh, ql, (u16*)nullptr, 0);
  hipLaunchKernelGGL(proj_kernel, dim3(8, 128, 1), blk, 0, stream, ctx, Wk, bk, kh, (u16*)nullptr, (u16*)nullptr, 2);
  hipLaunchKernelGGL(proj_kernel, dim3(8, 128, 1), blk, 0, stream, ctx, Wv, bv, (u16*)nullptr, (u16*)nullptr, vt, 1);
  hipLaunchKernelGGL(score_kernel, dim3(16, 16, 8), blk, 0, stream, qh, ql, kh, S);
  hipLaunchKernelGGL(softmax_kernel, dim3(16384, 1, 1), blk, 0, stream, S);
  hipLaunchKernelGGL(pv_kernel, dim3(8, 16, 8), blk, 0, stream, (const u16*)S, vt, out);
}

// Round 3
// 599.249 us; speedup vs baseline: 1.3951x; 1.3951x over previous
//
#include <hip/hip_runtime.h>
#include <hip/hip_bf16.h>
#include <hip/hip_fp16.h>

typedef float f32x4 __attribute__((ext_vector_type(4)));
typedef short short8 __attribute__((ext_vector_type(8)));
typedef _Float16 h4 __attribute__((ext_vector_type(4)));
typedef unsigned short u16;
typedef unsigned int u32;

#define LDK 40  // padded LDS k-stride (u16): 80B rows

__device__ __forceinline__ u16 bf16_rne(float x) {
  u32 u = __float_as_uint(x);
  u += 0x7FFFu + ((u >> 16) & 1u);
  return (u16)(u >> 16);
}
__device__ __forceinline__ u32 pack2(float a, float b) {
  return (u32)bf16_rne(a) | ((u32)bf16_rne(b) << 16);
}

// ---------------------------------------------------------------------------
// convert: fp32 -> bf16 RNE for x, ctx, Wq, Wk, Wv.  2048 elems/block.
// blocks: x[0,8192) ctx[8192,16384) wq[16384,16896) wk[..17408) wv[..17920)
// ---------------------------------------------------------------------------
__global__ __launch_bounds__(256)
void convert_kernel(const float* __restrict__ x, const float* __restrict__ ctx,
                    const float* __restrict__ wq, const float* __restrict__ wk,
                    const float* __restrict__ wv,
                    u16* __restrict__ xb, u16* __restrict__ cb,
                    u16* __restrict__ wqb, u16* __restrict__ wkb,
                    u16* __restrict__ wvb)
{
  int blk = blockIdx.x;
  const float* src; u16* dst; size_t off;
  if (blk < 8192)       { src = x;   dst = xb;  off = (size_t)blk * 2048; }
  else if (blk < 16384) { src = ctx; dst = cb;  off = (size_t)(blk - 8192) * 2048; }
  else if (blk < 16896) { src = wq;  dst = wqb; off = (size_t)(blk - 16384) * 2048; }
  else if (blk < 17408) { src = wk;  dst = wkb; off = (size_t)(blk - 16896) * 2048; }
  else                  { src = wv;  dst = wvb; off = (size_t)(blk - 17408) * 2048; }
  size_t e = off + (size_t)threadIdx.x * 8;
  float4 a = *(const float4*)(src + e);
  float4 b = *(const float4*)(src + e + 4);
  uint4 o;
  o.x = pack2(a.x, a.y); o.y = pack2(a.z, a.w);
  o.z = pack2(b.x, b.y); o.w = pack2(b.z, b.w);
  *(uint4*)(dst + e) = o;
}

// ---------------------------------------------------------------------------
// shared GEMM pieces: 128x128 tile, BK=32, 4 waves of 64x64, 16x16x32 bf16
// ---------------------------------------------------------------------------
__device__ __forceinline__ void stage_tile(const u16* __restrict__ G, int ld,
                                           int kt, u16* L, int tid) {
#pragma unroll
  for (int it = 0; it < 2; ++it) {
    int s = tid + 256 * it;
    int r = s >> 2, c = s & 3;
    *(uint4*)&L[r * LDK + c * 8] = *(const uint4*)(G + (size_t)r * ld + kt + c * 8);
  }
}

#define GEMM_FRAGS_AND_MFMA(Ah, Bh)                                            \
  short8 a_f[4], b_f[4];                                                       \
  _Pragma("unroll")                                                            \
  for (int i = 0; i < 4; ++i) {                                                \
    a_f[i] = *(const short8*)&Ah[(wm + i * 16 + lrow) * LDK + quad * 8];       \
    b_f[i] = *(const short8*)&Bh[(wn + i * 16 + lrow) * LDK + quad * 8];       \
  }                                                                            \
  _Pragma("unroll")                                                            \
  for (int i = 0; i < 4; ++i)                                                  \
    _Pragma("unroll")                                                          \
    for (int j = 0; j < 4; ++j)                                                \
      acc[i][j] = __builtin_amdgcn_mfma_f32_16x16x32_bf16(a_f[i], b_f[j], acc[i][j], 0, 0, 0);

#define GEMM_PROLOGUE                                                          \
  const int tid = threadIdx.x;                                                 \
  const int w = tid >> 6, lane = tid & 63;                                     \
  const int wm = (w >> 1) * 64, wn = (w & 1) * 64;                             \
  const int lrow = lane & 15, quad = lane >> 4;                                \
  f32x4 acc[4][4];                                                             \
  _Pragma("unroll")                                                            \
  for (int i = 0; i < 4; ++i)                                                  \
    _Pragma("unroll")                                                          \
    for (int j = 0; j < 4; ++j) {                                              \
      f32x4 z = {0.f, 0.f, 0.f, 0.f};                                          \
      acc[i][j] = z;                                                           \
    }

// ---------------------------------------------------------------------------
// projq: Y[M,1024] bf16 = A[M,1024] @ W[1024,1024]^T + bias   (q and k)
// ---------------------------------------------------------------------------
__global__ __launch_bounds__(256)
void projq_kernel(const u16* __restrict__ A, const u16* __restrict__ W,
                  const float* __restrict__ bias, u16* __restrict__ Y)
{
  __shared__ __align__(16) u16 Ah[128 * LDK];
  __shared__ __align__(16) u16 Bh[128 * LDK];
  const int m0 = blockIdx.y * 128, n0 = blockIdx.x * 128;
  GEMM_PROLOGUE
  const u16* A_b = A + (size_t)m0 * 1024;
  const u16* B_b = W + (size_t)n0 * 1024;

  for (int kt = 0; kt < 1024; kt += 32) {
    __syncthreads();
    stage_tile(A_b, 1024, kt, Ah, tid);
    stage_tile(B_b, 1024, kt, Bh, tid);
    __syncthreads();
    GEMM_FRAGS_AND_MFMA(Ah, Bh)
  }

#pragma unroll
  for (int j = 0; j < 4; ++j) {
    int gn = n0 + wn + j * 16 + lrow;
    float bj = bias[gn];
#pragma unroll
    for (int i = 0; i < 4; ++i) {
      int gm_base = m0 + wm + i * 16 + quad * 4;
#pragma unroll
      for (int r = 0; r < 4; ++r)
        Y[(size_t)(gm_base + r) * 1024 + gn] = bf16_rne(acc[i][j][r] + bj);
    }
  }
}

// ---------------------------------------------------------------------------
// projv: Vt[b][e][t] bf16 = (ctx @ Wv^T + bv) transposed, via LDS bounce.
// ---------------------------------------------------------------------------
__global__ __launch_bounds__(256)
void projv_kernel(const u16* __restrict__ A, const u16* __restrict__ W,
                  const float* __restrict__ bias, u16* __restrict__ Vt)
{
  __shared__ __align__(16) u16 smem[128 * 136];  // 34816 B; staging uses first 20480 B
  u16* Ah = smem;
  u16* Bh = smem + 128 * LDK;
  const int m0 = blockIdx.y * 128, n0 = blockIdx.x * 128;
  const int bb = m0 >> 11, t0 = m0 & 2047;
  GEMM_PROLOGUE
  const u16* A_b = A + (size_t)m0 * 1024;
  const u16* B_b = W + (size_t)n0 * 1024;

  for (int kt = 0; kt < 1024; kt += 32) {
    __syncthreads();
    stage_tile(A_b, 1024, kt, Ah, tid);
    stage_tile(B_b, 1024, kt, Bh, tid);
    __syncthreads();
    GEMM_FRAGS_AND_MFMA(Ah, Bh)
  }

  // transpose via LDS: T[e_local][t_local], stride 136 u16
  __syncthreads();
  u16* T = smem;
#pragma unroll
  for (int j = 0; j < 4; ++j) {
    int e_l = wn + j * 16 + lrow;
    float bj = bias[n0 + e_l];
#pragma unroll
    for (int i = 0; i < 4; ++i) {
      int t_l = wm + i * 16 + quad * 4;
      uint2 p;
      p.x = pack2(acc[i][j][0] + bj, acc[i][j][1] + bj);
      p.y = pack2(acc[i][j][2] + bj, acc[i][j][3] + bj);
      *(uint2*)&T[e_l * 136 + t_l] = p;
    }
  }
  __syncthreads();

  // coalesced write: 2 threads per e-row, 8 x 16B each
  int e_l = tid >> 1, half = tid & 1;
  u16* gdst = Vt + ((size_t)(bb * 1024 + n0 + e_l)) * 2048 + t0 + half * 64;
  const u16* Trow = &T[e_l * 136 + half * 64];
#pragma unroll
  for (int k = 0; k < 8; ++k)
    *(uint4*)(gdst + k * 8) = *(const uint4*)(Trow + k * 8);
}

// ---------------------------------------------------------------------------
// score: S[b,s,t] fp16 = scale * (q[b] @ k[b]^T)
// ---------------------------------------------------------------------------
__global__ __launch_bounds__(256)
void score_kernel(const u16* __restrict__ qb, const u16* __restrict__ kb,
                  _Float16* __restrict__ S)
{
  __shared__ __align__(16) u16 Ah[128 * LDK];
  __shared__ __align__(16) u16 Bh[128 * LDK];
  const int b = blockIdx.z;
  const int m0 = blockIdx.y * 128, n0 = blockIdx.x * 128;
  GEMM_PROLOGUE
  const u16* A_b = qb + ((size_t)b * 2048 + m0) * 1024;
  const u16* B_b = kb + ((size_t)b * 2048 + n0) * 1024;

  for (int kt = 0; kt < 1024; kt += 32) {
    __syncthreads();
    stage_tile(A_b, 1024, kt, Ah, tid);
    stage_tile(B_b, 1024, kt, Bh, tid);
    __syncthreads();
    GEMM_FRAGS_AND_MFMA(Ah, Bh)
  }

  const float scale = 0.03125f;  // 1/sqrt(1024)
#pragma unroll
  for (int j = 0; j < 4; ++j) {
    int gn = n0 + wn + j * 16 + lrow;
#pragma unroll
    for (int i = 0; i < 4; ++i) {
      int gm_base = m0 + wm + i * 16 + quad * 4;
#pragma unroll
      for (int r = 0; r < 4; ++r)
        S[((size_t)b * 2048 + gm_base + r) * 2048 + gn] = (_Float16)(acc[i][j][r] * scale);
    }
  }
}

// ---------------------------------------------------------------------------
// softmax over S rows (fp16 in), writes P bf16 in place (same 4096B row).
// ---------------------------------------------------------------------------
__global__ __launch_bounds__(256)
void softmax_kernel(_Float16* __restrict__ S)
{
  const int row = blockIdx.x;
  const int tid = threadIdx.x;
  _Float16* Sr = S + (size_t)row * 2048;
  h4 ah = *(const h4*)(Sr + tid * 4);
  h4 bh = *(const h4*)(Sr + 1024 + tid * 4);
  float a0 = (float)ah.x, a1 = (float)ah.y, a2 = (float)ah.z, a3 = (float)ah.w;
  float b0 = (float)bh.x, b1 = (float)bh.y, b2 = (float)bh.z, b3 = (float)bh.w;

  float m = fmaxf(fmaxf(fmaxf(a0, a1), fmaxf(a2, a3)),
                  fmaxf(fmaxf(b0, b1), fmaxf(b2, b3)));
#pragma unroll
  for (int off = 32; off > 0; off >>= 1) m = fmaxf(m, __shfl_xor(m, off));

  __shared__ float red[4];
  const int wid = tid >> 6, lane = tid & 63;
  if (lane == 0) red[wid] = m;
  __syncthreads();
  m = fmaxf(fmaxf(red[0], red[1]), fmaxf(red[2], red[3]));

  float e0 = __expf(a0 - m), e1 = __expf(a1 - m), e2 = __expf(a2 - m), e3 = __expf(a3 - m);
  float e4 = __expf(b0 - m), e5 = __expf(b1 - m), e6 = __expf(b2 - m), e7 = __expf(b3 - m);
  float s = ((e0 + e1) + (e2 + e3)) + ((e4 + e5) + (e6 + e7));
#pragma unroll
  for (int off = 32; off > 0; off >>= 1) s += __shfl_xor(s, off);
  __syncthreads();
  if (lane == 0) red[wid] = s;
  __syncthreads();
  s = red[0] + red[1] + red[2] + red[3];
  float inv = 1.0f / s;

  u16* P = (u16*)S;
  size_t pb = (size_t)row * 2048;
  uint2 w0, w1;
  w0.x = pack2(e0 * inv, e1 * inv);
  w0.y = pack2(e2 * inv, e3 * inv);
  w1.x = pack2(e4 * inv, e5 * inv);
  w1.y = pack2(e6 * inv, e7 * inv);
  *(uint2*)&P[pb + tid * 4] = w0;
  *(uint2*)&P[pb + 1024 + tid * 4] = w1;
}

// ---------------------------------------------------------------------------
// pv: O[b,s,e] fp32 = P[b] @ Vt[b]^T   (P row stride 2048, Vt row stride 2048)
// ---------------------------------------------------------------------------
__global__ __launch_bounds__(256)
void pv_kernel(const u16* __restrict__ P, const u16* __restrict__ Vt,
               float* __restrict__ O)
{
  __shared__ __align__(16) u16 Ah[128 * LDK];
  __shared__ __align__(16) u16 Bh[128 * LDK];
  const int b = blockIdx.z;
  const int m0 = blockIdx.y * 128, n0 = blockIdx.x * 128;
  GEMM_PROLOGUE
  const u16* A_b = P + ((size_t)b * 2048 + m0) * 2048;
  const u16* B_b = Vt + ((size_t)b * 1024 + n0) * 2048;

  for (int kt = 0; kt < 2048; kt += 32) {
    __syncthreads();
    stage_tile(A_b, 2048, kt, Ah, tid);
    stage_tile(B_b, 2048, kt, Bh, tid);
    __syncthreads();
    GEMM_FRAGS_AND_MFMA(Ah, Bh)
  }

#pragma unroll
  for (int j = 0; j < 4; ++j) {
    int gn = n0 + wn + j * 16 + lrow;
#pragma unroll
    for (int i = 0; i < 4; ++i) {
      int gm_base = m0 + wm + i * 16 + quad * 4;
#pragma unroll
      for (int r = 0; r < 4; ++r)
        O[((size_t)b * 2048 + gm_base + r) * 1024 + gn] = acc[i][j][r];
    }
  }
}

// ---------------------------------------------------------------------------
extern "C" void kernel_launch(void* const* d_in, const int* in_sizes, int n_in,
                              void* d_out, int out_size, void* d_ws, size_t ws_size,
                              hipStream_t stream) {
  const float* x   = (const float*)d_in[0];
  const float* ctx = (const float*)d_in[1];
  const float* Wq  = (const float*)d_in[2];
  const float* bq  = (const float*)d_in[3];
  const float* Wk  = (const float*)d_in[4];
  const float* bk  = (const float*)d_in[5];
  const float* Wv  = (const float*)d_in[6];
  const float* bv  = (const float*)d_in[7];
  float* out = (float*)d_out;

  // ws layout (u16 elems): [xb 16.8M][cb 16.8M][qb][kb][vt][wqb 1M][wkb][wvb]
  // S (fp16, 33.5M elems = 64 MiB) aliases [xb cb] (dead after proj).
  const size_t NQ = (size_t)16384 * 1024;   // 16.8M
  const size_t NW = (size_t)1024 * 1024;    // 1M
  const size_t needed = (5 * NQ + 3 * NW) * sizeof(u16);  // ~174 MiB
  if (ws_size < needed) return;

  u16* xb  = (u16*)d_ws;
  u16* cb  = xb + NQ;
  u16* qb  = cb + NQ;
  u16* kb  = qb + NQ;
  u16* vt  = kb + NQ;
  u16* wqb = vt + NQ;
  u16* wkb = wqb + NW;
  u16* wvb = wkb + NW;
  _Float16* S = (_Float16*)d_ws;  // aliases xb+cb after projections complete

  dim3 blk(256, 1, 1);
  hipLaunchKernelGGL(convert_kernel, dim3(17920, 1, 1), blk, 0, stream,
                     x, ctx, Wq, Wk, Wv, xb, cb, wqb, wkb, wvb);
  hipLaunchKernelGGL(projq_kernel, dim3(8, 128, 1), blk, 0, stream, xb, wqb, bq, qb);
  hipLaunchKernelGGL(projq_kernel, dim3(8, 128, 1), blk, 0, stream, cb, wkb, bk, kb);
  hipLaunchKernelGGL(projv_kernel, dim3(8, 128, 1), blk, 0, stream, cb, wvb, bv, vt);
  hipLaunchKernelGGL(score_kernel, dim3(16, 16, 8), blk, 0, stream, qb, kb, S);
  hipLaunchKernelGGL(softmax_kernel, dim3(16384, 1, 1), blk, 0, stream, S);
  hipLaunchKernelGGL(pv_kernel, dim3(8, 16, 8), blk, 0, stream, (const u16*)S, vt, out);
}